// Round 6
// baseline (79.756 us; speedup 1.0000x reference)
//
#include <hip/hip_runtime.h>
#include <hip/hip_bf16.h>
#include <math.h>

#define BB 8
#define TT 2048
#define DD 512
#define NPAN 32   // 64-row panels per batch
#define NSLOT 18  // partial slots: 0=own(h0), 1..16=col contribs, 17=own(h1)

typedef __attribute__((ext_vector_type(8))) short bf16x8;
typedef __attribute__((ext_vector_type(4))) float f32x4;

__device__ inline float softplus_f(float v) { return log1pf(expf(v)); }

// fast tanh: 1 - 2/(exp2(2*log2e*y)+1); v_exp_f32 + v_rcp_f32, ~1e-6 rel err
__device__ inline float tanh_fast(float y) {
    float e = __builtin_amdgcn_exp2f(y * 2.8853900817779268f);
    return 1.0f - 2.0f * __builtin_amdgcn_rcpf(e + 1.0f);
}
__device__ inline float exp_fast(float y) {
    return __builtin_amdgcn_exp2f(y * 1.4426950408889634f);
}

// fp32 -> bf16 round-nearest-even on bit pattern
__device__ inline unsigned short f2bf(float f) {
    unsigned int u = __float_as_uint(f);
    unsigned int r = (u + 0x7fffu + ((u >> 16) & 1u)) >> 16;
    return (unsigned short)r;
}
__device__ inline float bf2f(unsigned short h) {
    unsigned int u = ((unsigned int)h) << 16;
    return __uint_as_float(u);
}

__device__ inline void load_lds16(const void* g, void* l) {
    __builtin_amdgcn_global_load_lds(
        (const __attribute__((address_space(1))) unsigned int*)g,
        (__attribute__((address_space(3))) unsigned int*)l, 16, 0, 0);
}

// ---------------- K1: fused prep + per-row elementwise + reductions ----------------
// 256 threads = 4 waves; one wave per row of D=512; 8 elems/thread.
// Writes XN (normalized x, bf16) and PO (gelu*gate_hist*gate_cos, bf16).
__global__ __launch_bounds__(256) void k1_elem(
    const float* __restrict__ x, const float* __restrict__ ema_mean,
    const float* __restrict__ ema_sq, const float* __restrict__ ema_out,
    const float* __restrict__ p_log_tau, const float* __restrict__ p_lbu,
    const float* __restrict__ p_lbd, const float* __restrict__ p_lg,
    unsigned short* __restrict__ xn, unsigned short* __restrict__ po) {
    const int row = blockIdx.x * 4 + (threadIdx.x >> 6);
    const int lane = threadIdx.x & 63;
    const size_t base = (size_t)row * DD;

    const float tau = expf(p_log_tau[0]);
    const float beta_up = softplus_f(p_lbu[0]);
    const float beta_dn = softplus_f(p_lbd[0]);
    const float gamma = softplus_f(p_lg[0]);

    float xv[8], pg[8];
    float sx2 = 0.f, so2 = 0.f, sod = 0.f, se2 = 0.f;
#pragma unroll
    for (int c = 0; c < 2; ++c) {
        const int j0 = c * 256 + lane * 4;
        float4 xx = *reinterpret_cast<const float4*>(x + base + j0);
        float4 mm = *reinterpret_cast<const float4*>(ema_mean + j0);
        float4 qq = *reinterpret_cast<const float4*>(ema_sq + j0);
        float4 eo = *reinterpret_cast<const float4*>(ema_out + j0);
        float vv[4] = {xx.x, xx.y, xx.z, xx.w};
        float vm[4] = {mm.x, mm.y, mm.z, mm.w};
        float vq[4] = {qq.x, qq.y, qq.z, qq.w};
        float ve[4] = {eo.x, eo.y, eo.z, eo.w};
#pragma unroll
        for (int q = 0; q < 4; ++q) {
            const int e = c * 4 + q;
            float xf = vv[q];
            xv[e] = xf;
            // gelu (tanh approx)
            float x3 = xf * xf * xf;
            float gl = 0.5f * xf * (1.0f + tanh_fast(0.7978845608028654f * (xf + 0.044715f * x3)));
            // z-gate (inv_std inline)
            float var = fmaxf(vq[q] - vm[q] * vm[q], 1e-4f);
            float istd = __builtin_amdgcn_rcpf(sqrtf(var) + 1e-5f);
            float z = (xf - vm[q]) * istd;
            float th = tanh_fast(gamma * z);
            float up = beta_up * fmaxf(th, 0.0f);
            float dn = beta_dn * fmaxf(-th, 0.0f);
            float gh = fminf(fmaxf(1.0f + up - dn, 0.05f), 8.0f);
            pg[e] = gl * gh;
            sx2 += xf * xf;
            so2 += gl * gl;
            sod += gl * ve[q];
            se2 += ve[q] * ve[q];
        }
    }
#pragma unroll
    for (int off = 32; off; off >>= 1) {
        sx2 += __shfl_xor(sx2, off);
        so2 += __shfl_xor(so2, off);
        sod += __shfl_xor(sod, off);
        se2 += __shfl_xor(se2, off);
    }
    const float inv_xnorm = __builtin_amdgcn_rcpf(fmaxf(sqrtf(sx2), 1e-12f));
    const float inv_en = __builtin_amdgcn_rcpf(fmaxf(sqrtf(se2), 1e-12f));
    float cosv = sod * inv_en * __builtin_amdgcn_rcpf(fmaxf(sqrtf(so2), 1e-12f));
    cosv = fminf(fmaxf(cosv, -1.0f), 1.0f);
    const float gcos = exp_fast(-tau * cosv);

#pragma unroll
    for (int c = 0; c < 2; ++c) {
        const int j0 = c * 256 + lane * 4;
        ushort4 pb;
        pb.x = f2bf(pg[c * 4 + 0] * gcos);
        pb.y = f2bf(pg[c * 4 + 1] * gcos);
        pb.z = f2bf(pg[c * 4 + 2] * gcos);
        pb.w = f2bf(pg[c * 4 + 3] * gcos);
        *reinterpret_cast<ushort4*>(po + base + j0) = pb;
        ushort4 xb;
        xb.x = f2bf(xv[c * 4 + 0] * inv_xnorm);
        xb.y = f2bf(xv[c * 4 + 1] * inv_xnorm);
        xb.z = f2bf(xv[c * 4 + 2] * inv_xnorm);
        xb.w = f2bf(xv[c * 4 + 3] * inv_xnorm);
        *reinterpret_cast<ushort4*>(xn + base + j0) = xb;
    }
}

// ---------------- K2: sim row/col max via MFMA, A-panel-resident, barrier-free loop ----
// Block = (b, p, h): batch b (XCD-pinned: b = bid&7), 64-row panel p, half h.
// A-panel (64 x 512 bf16 = 64 KB) staged once into XOR-swizzled LDS.
// Cyclic symmetric pairing: panel pair {p, (p+k)&31} computed once, k = 1..16
// (k=16 only when p<16); k=0 is the diagonal chunk (masked). h splits k-range:
// h0 -> k=0..8, h1 -> k=9..16 (p<16) / 9..15 (p>=16).
// Each wave independently processes its share of chunks: 64x64 GEMM vs LDS-A,
// B read DIRECT from global (L2-resident, XCD-pinned) -> no barriers in loop.
// Emits: running row-max (slot 0 / 17), per-chunk col-max -> slot k.
__global__ __launch_bounds__(256, 2) void k2_nn(const unsigned short* __restrict__ xn,
                                                float* __restrict__ partial) {
    __shared__ short As[64 * 512];
    __shared__ float rbuf[4][64];

    const int tid = threadIdx.x;
    const int wave = tid >> 6;
    const int lane = tid & 63;
    const int r15 = lane & 15;
    const int kgrp = lane >> 4;

    const int bid = blockIdx.x;
    const int b = bid & 7;            // XCD pin
    const int p = (bid >> 3) & 31;    // row panel
    const int h = bid >> 8;           // half of the cyclic range

    const size_t bbase = (size_t)b * TT * DD;
    const unsigned short* Pg = xn + bbase + (size_t)p * 64 * DD;

    // ---- stage A panel: 16 rounds; wave stages row r*4+wave each round ----
    // linear LDS dest (row*1024 + lane*16); source inverse-swizzled (rule 21):
    // logical colbyte cb = (lane*16) ^ ((row&7)<<4)
#pragma unroll
    for (int r = 0; r < 16; ++r) {
        const int row = r * 4 + wave;
        const int cb = (lane * 16) ^ ((row & 7) << 4);
        load_lds16(Pg + (size_t)row * DD + (cb >> 1), (char*)As + row * 1024);
    }
    __syncthreads();  // drains vmcnt(0): A resident. Last barrier until epilogue.

    const int nk = (h == 0) ? 9 : ((p < 16) ? 8 : 7);
    const int kbase = h * 9;

    float rmax[4][4];
#pragma unroll
    for (int mi = 0; mi < 4; ++mi)
#pragma unroll
        for (int r = 0; r < 4; ++r) rmax[mi][r] = -2.0f;

    for (int idx = wave; idx < nk; idx += 4) {
        const int k = kbase + idx;
        const int c = (p + k) & 31;
        const unsigned short* Bg = xn + bbase + (size_t)c * 64 * DD;

        f32x4 acc[4][4];
#pragma unroll
        for (int mi = 0; mi < 4; ++mi)
#pragma unroll
            for (int ni = 0; ni < 4; ++ni) acc[mi][ni] = (f32x4){0.f, 0.f, 0.f, 0.f};

#pragma unroll 4
        for (int kk = 0; kk < 16; ++kk) {
            bf16x8 av[4], bv[4];
#pragma unroll
            for (int mi = 0; mi < 4; ++mi) {
                const int row = mi * 16 + r15;
                const int off = row * 1024 + ((kk * 64 + kgrp * 16) ^ ((row & 7) << 4));
                av[mi] = *(const bf16x8*)((const char*)As + off);
            }
#pragma unroll
            for (int ni = 0; ni < 4; ++ni)
                bv[ni] = *(const bf16x8*)(Bg + (size_t)(ni * 16 + r15) * DD + kk * 32 + kgrp * 8);
#pragma unroll
            for (int mi = 0; mi < 4; ++mi)
#pragma unroll
                for (int ni = 0; ni < 4; ++ni)
                    acc[mi][ni] = __builtin_amdgcn_mfma_f32_16x16x32_bf16(av[mi], bv[ni],
                                                                          acc[mi][ni], 0, 0, 0);
        }

        // D layout: col = ni*16 + r15, row = mi*16 + kgrp*4 + r  [R3-verified]
        if (k == 0) {
            // diagonal chunk: mask sim(i,i) = -2
#pragma unroll
            for (int mi = 0; mi < 4; ++mi)
#pragma unroll
                for (int r = 0; r < 4; ++r)
                    if (r15 == kgrp * 4 + r) acc[mi][mi][r] = -2.0f;
        } else {
            // col-max of this chunk -> partial slot k (mirror contribution)
#pragma unroll
            for (int ni = 0; ni < 4; ++ni) {
                float v = -2.0f;
#pragma unroll
                for (int mi = 0; mi < 4; ++mi)
#pragma unroll
                    for (int r = 0; r < 4; ++r) v = fmaxf(v, acc[mi][ni][r]);
                v = fmaxf(v, __shfl_xor(v, 16));
                v = fmaxf(v, __shfl_xor(v, 32));
                if (kgrp == 0)
                    partial[((size_t)b * TT + c * 64 + ni * 16 + r15) * NSLOT + k] = v;
            }
        }
        // fold into running row-max (cols folded per-lane; r15 reduce deferred)
#pragma unroll
        for (int mi = 0; mi < 4; ++mi)
#pragma unroll
            for (int r = 0; r < 4; ++r) {
                float v = rmax[mi][r];
#pragma unroll
                for (int ni = 0; ni < 4; ++ni) v = fmaxf(v, acc[mi][ni][r]);
                rmax[mi][r] = v;
            }
    }

    // ---- epilogue: reduce row-max over the 16 col-lanes, then across waves ----
#pragma unroll
    for (int mi = 0; mi < 4; ++mi)
#pragma unroll
        for (int r = 0; r < 4; ++r) {
            float v = rmax[mi][r];
            v = fmaxf(v, __shfl_xor(v, 1));
            v = fmaxf(v, __shfl_xor(v, 2));
            v = fmaxf(v, __shfl_xor(v, 4));
            v = fmaxf(v, __shfl_xor(v, 8));
            rmax[mi][r] = v;
        }
    if (r15 == 0) {
#pragma unroll
        for (int mi = 0; mi < 4; ++mi)
#pragma unroll
            for (int r = 0; r < 4; ++r) rbuf[wave][mi * 16 + kgrp * 4 + r] = rmax[mi][r];
    }
    __syncthreads();
    if (tid < 64) {
        const float v = fmaxf(fmaxf(rbuf[0][tid], rbuf[1][tid]),
                              fmaxf(rbuf[2][tid], rbuf[3][tid]));
        partial[((size_t)b * TT + p * 64 + tid) * NSLOT + (h ? 17 : 0)] = v;
    }
}

// ---------------- K3: reduce partial maxes + gate_nn scale + final write ----------------
// 256 threads = 4 waves; one wave per row; reads bf16 PO, writes f32 out.
__global__ __launch_bounds__(256) void k3_scale(float* __restrict__ out,
                                                const unsigned short* __restrict__ po,
                                                const float* __restrict__ partial,
                                                const float* __restrict__ p_lsn,
                                                const float* __restrict__ p_lwn) {
    const int row = blockIdx.x * 4 + (threadIdx.x >> 6);
    const int lane = threadIdx.x & 63;
    const float sigma_nn = softplus_f(p_lsn[0]);
    const float w_nn = softplus_f(p_lwn[0]);

    const int q = (row & (TT - 1)) >> 6;  // panel within batch
    float v = -2.0f;
    if (lane < NSLOT && !(lane == 16 && q < 16))
        v = partial[(size_t)row * NSLOT + lane];
    v = fmaxf(v, __shfl_xor(v, 1));
    v = fmaxf(v, __shfl_xor(v, 2));
    v = fmaxf(v, __shfl_xor(v, 4));
    v = fmaxf(v, __shfl_xor(v, 8));
    v = fmaxf(v, __shfl_xor(v, 16));
    v = fmaxf(v, __shfl_xor(v, 32));
    const float g = 1.0f + w_nn * tanh_fast(sigma_nn * 0.5f * (1.0f - v));

    const size_t base = (size_t)row * DD + lane * 8;
    ushort4 p0 = *reinterpret_cast<const ushort4*>(po + base);
    ushort4 p1 = *reinterpret_cast<const ushort4*>(po + base + 4);
    float4 o0, o1;
    o0.x = bf2f(p0.x) * g; o0.y = bf2f(p0.y) * g;
    o0.z = bf2f(p0.z) * g; o0.w = bf2f(p0.w) * g;
    o1.x = bf2f(p1.x) * g; o1.y = bf2f(p1.y) * g;
    o1.z = bf2f(p1.z) * g; o1.w = bf2f(p1.w) * g;
    *reinterpret_cast<float4*>(out + base) = o0;
    *reinterpret_cast<float4*>(out + base + 4) = o1;
}

extern "C" void kernel_launch(void* const* d_in, const int* in_sizes, int n_in,
                              void* d_out, int out_size, void* d_ws, size_t ws_size,
                              hipStream_t stream) {
    const float* x = (const float*)d_in[0];
    const float* ema_mean = (const float*)d_in[1];
    const float* ema_sq = (const float*)d_in[2];
    const float* ema_out = (const float*)d_in[3];
    const float* log_tau = (const float*)d_in[4];
    const float* log_beta_up = (const float*)d_in[5];
    const float* log_beta_dn = (const float*)d_in[6];
    const float* log_gamma = (const float*)d_in[7];
    const float* log_sigma_nn = (const float*)d_in[8];
    const float* log_w_nn = (const float*)d_in[9];

    // ws layout: XN bf16 [B*T*D] (16.78 MB) | PO bf16 [B*T*D] (16.78 MB)
    //            | partial f32[B*T][NSLOT] (1.18 MB)
    char* ws = (char*)d_ws;
    unsigned short* XN = (unsigned short*)ws;
    unsigned short* PO = (unsigned short*)(ws + 16777216);
    float* partial = (float*)(ws + 33554432);
    float* out = (float*)d_out;

    hipLaunchKernelGGL(k1_elem, dim3(BB * TT / 4), dim3(256), 0, stream, x, ema_mean, ema_sq,
                       ema_out, log_tau, log_beta_up, log_beta_dn, log_gamma, XN, PO);
    hipLaunchKernelGGL(k2_nn, dim3(BB * NPAN * 2), dim3(256), 0, stream, XN, partial);
    hipLaunchKernelGGL(k3_scale, dim3(BB * TT / 4), dim3(256), 0, stream, out, PO, partial,
                       log_sigma_nn, log_w_nn);
}

// Round 7
// 76.656 us; speedup vs baseline: 1.0404x; 1.0404x over previous
//
#include <hip/hip_runtime.h>
#include <hip/hip_bf16.h>
#include <math.h>

#define BB 8
#define TT 2048
#define DD 512
#define NT2 8   // 256-col tiles per batch row

typedef __attribute__((ext_vector_type(8))) short bf16x8;
typedef __attribute__((ext_vector_type(4))) float f32x4;

__device__ inline float softplus_f(float v) { return log1pf(expf(v)); }

// fast tanh: 1 - 2/(exp2(2*log2e*y)+1); v_exp_f32 + v_rcp_f32, ~1e-6 rel err
__device__ inline float tanh_fast(float y) {
    float e = __builtin_amdgcn_exp2f(y * 2.8853900817779268f);
    return 1.0f - 2.0f * __builtin_amdgcn_rcpf(e + 1.0f);
}
__device__ inline float exp_fast(float y) {
    return __builtin_amdgcn_exp2f(y * 1.4426950408889634f);
}

// fp32 -> bf16 round-nearest-even on bit pattern
__device__ inline unsigned short f2bf(float f) {
    unsigned int u = __float_as_uint(f);
    unsigned int r = (u + 0x7fffu + ((u >> 16) & 1u)) >> 16;
    return (unsigned short)r;
}
__device__ inline float bf2f(unsigned short h) {
    unsigned int u = ((unsigned int)h) << 16;
    return __uint_as_float(u);
}

__device__ inline void load_lds16(const void* g, void* l) {
    __builtin_amdgcn_global_load_lds(
        (const __attribute__((address_space(1))) unsigned int*)g,
        (__attribute__((address_space(3))) unsigned int*)l, 16, 0, 0);
}

// ---------------- K1: fused prep + per-row elementwise + reductions ----------------
// 256 threads = 4 waves; one wave per row of D=512; 8 elems/thread.
// Writes XN (normalized x, bf16) and PO (gelu*gate_hist*gate_cos, bf16).
__global__ __launch_bounds__(256) void k1_elem(
    const float* __restrict__ x, const float* __restrict__ ema_mean,
    const float* __restrict__ ema_sq, const float* __restrict__ ema_out,
    const float* __restrict__ p_log_tau, const float* __restrict__ p_lbu,
    const float* __restrict__ p_lbd, const float* __restrict__ p_lg,
    unsigned short* __restrict__ xn, unsigned short* __restrict__ po) {
    const int row = blockIdx.x * 4 + (threadIdx.x >> 6);
    const int lane = threadIdx.x & 63;
    const size_t base = (size_t)row * DD;

    const float tau = expf(p_log_tau[0]);
    const float beta_up = softplus_f(p_lbu[0]);
    const float beta_dn = softplus_f(p_lbd[0]);
    const float gamma = softplus_f(p_lg[0]);

    float xv[8], pg[8];
    float sx2 = 0.f, so2 = 0.f, sod = 0.f, se2 = 0.f;
#pragma unroll
    for (int c = 0; c < 2; ++c) {
        const int j0 = c * 256 + lane * 4;
        float4 xx = *reinterpret_cast<const float4*>(x + base + j0);
        float4 mm = *reinterpret_cast<const float4*>(ema_mean + j0);
        float4 qq = *reinterpret_cast<const float4*>(ema_sq + j0);
        float4 eo = *reinterpret_cast<const float4*>(ema_out + j0);
        float vv[4] = {xx.x, xx.y, xx.z, xx.w};
        float vm[4] = {mm.x, mm.y, mm.z, mm.w};
        float vq[4] = {qq.x, qq.y, qq.z, qq.w};
        float ve[4] = {eo.x, eo.y, eo.z, eo.w};
#pragma unroll
        for (int q = 0; q < 4; ++q) {
            const int e = c * 4 + q;
            float xf = vv[q];
            xv[e] = xf;
            // gelu (tanh approx)
            float x3 = xf * xf * xf;
            float gl = 0.5f * xf * (1.0f + tanh_fast(0.7978845608028654f * (xf + 0.044715f * x3)));
            // z-gate (inv_std inline)
            float var = fmaxf(vq[q] - vm[q] * vm[q], 1e-4f);
            float istd = __builtin_amdgcn_rcpf(sqrtf(var) + 1e-5f);
            float z = (xf - vm[q]) * istd;
            float th = tanh_fast(gamma * z);
            float up = beta_up * fmaxf(th, 0.0f);
            float dn = beta_dn * fmaxf(-th, 0.0f);
            float gh = fminf(fmaxf(1.0f + up - dn, 0.05f), 8.0f);
            pg[e] = gl * gh;
            sx2 += xf * xf;
            so2 += gl * gl;
            sod += gl * ve[q];
            se2 += ve[q] * ve[q];
        }
    }
#pragma unroll
    for (int off = 32; off; off >>= 1) {
        sx2 += __shfl_xor(sx2, off);
        so2 += __shfl_xor(so2, off);
        sod += __shfl_xor(sod, off);
        se2 += __shfl_xor(se2, off);
    }
    const float inv_xnorm = __builtin_amdgcn_rcpf(fmaxf(sqrtf(sx2), 1e-12f));
    const float inv_en = __builtin_amdgcn_rcpf(fmaxf(sqrtf(se2), 1e-12f));
    float cosv = sod * inv_en * __builtin_amdgcn_rcpf(fmaxf(sqrtf(so2), 1e-12f));
    cosv = fminf(fmaxf(cosv, -1.0f), 1.0f);
    const float gcos = exp_fast(-tau * cosv);

#pragma unroll
    for (int c = 0; c < 2; ++c) {
        const int j0 = c * 256 + lane * 4;
        ushort4 pb;
        pb.x = f2bf(pg[c * 4 + 0] * gcos);
        pb.y = f2bf(pg[c * 4 + 1] * gcos);
        pb.z = f2bf(pg[c * 4 + 2] * gcos);
        pb.w = f2bf(pg[c * 4 + 3] * gcos);
        *reinterpret_cast<ushort4*>(po + base + j0) = pb;
        ushort4 xb;
        xb.x = f2bf(xv[c * 4 + 0] * inv_xnorm);
        xb.y = f2bf(xv[c * 4 + 1] * inv_xnorm);
        xb.z = f2bf(xv[c * 4 + 2] * inv_xnorm);
        xb.w = f2bf(xv[c * 4 + 3] * inv_xnorm);
        *reinterpret_cast<ushort4*>(xn + base + j0) = xb;
    }
}

// ---------------- K2: sim row-max via MFMA, 256x256 tile ----------------
// 512 threads = 8 waves (2 row-groups x 4 col-groups). Per-wave output 128x64
// (acc[8][4] 16x16 fragments). BK=64, full-K-tile double-buffer: LDS exactly
// 128 KB (A/B x 2 sides, [256][64] bf16, XOR-swizzled byte^=(row&7)<<4 via
// pre-swizzled global source + linear gload_lds dest — R3-verified 0-conflict).
// T3 minimum recipe: STAGE(next) issued BEFORE COMPUTE(cur); one barrier per
// K-step. Arithmetic intensity 128 FLOP/staged-byte keeps staging (~26 B/cyc/CU)
// under per-XCD L2 BW (~45 B/cyc/CU) — the 128-tile versions were L2-BW-bound.
// Full matrix (no symmetry): 512 blocks = exactly 2 balanced rounds of 256 CUs.
// XCD pin: b = bid&7 keeps each batch's 2 MB panel set in one XCD's L2.
__global__ __launch_bounds__(512, 2) void k2_nn(const unsigned short* __restrict__ xn,
                                                float* __restrict__ partial) {
    __shared__ char lds[131072];  // A0 | B0 @+32768 | A1 @+65536 | B1 @+98304

    const int tid = threadIdx.x;
    const int wave = tid >> 6;
    const int lane = tid & 63;
    const int r15 = lane & 15;
    const int kgrp = lane >> 4;
    const int wr = wave >> 2;  // 0..1 (row half)
    const int wc = wave & 3;   // 0..3 (col quarter)

    const int bid = blockIdx.x;
    const int b = bid & 7;       // XCD pin
    const int t = bid >> 3;      // 0..63
    const int tm = t >> 3, tn = t & 7;

    const size_t bbase = (size_t)b * TT * DD;
    const unsigned short* Ag = xn + bbase + (size_t)tm * 256 * DD;
    const unsigned short* Bg = xn + bbase + (size_t)tn * 256 * DD;

    f32x4 acc[8][4];
#pragma unroll
    for (int i = 0; i < 8; ++i)
#pragma unroll
        for (int j = 0; j < 4; ++j) acc[i][j] = (f32x4){0.f, 0.f, 0.f, 0.f};

    // STAGE: 4 chunks of 8 KB per array (512 thr x 16 B). Linear dest byte o;
    // row = o>>7, logical col-byte = (o&127) ^ ((row&7)<<4)  (rule 21).
#define STAGE(S, KT)                                                          \
    do {                                                                      \
        _Pragma("unroll") for (int c = 0; c < 4; ++c) {                       \
            const int o = c * 8192 + tid * 16;                                \
            const int row = o >> 7;                                           \
            const int lb = (o & 127) ^ ((row & 7) << 4);                      \
            const size_t gof = (size_t)row * DD + (KT) * 64 + (lb >> 1);      \
            load_lds16(Ag + gof, lds + (S) * 65536 + o);                      \
            load_lds16(Bg + gof, lds + 32768 + (S) * 65536 + o);              \
        }                                                                     \
    } while (0)

#define COMPUTE(S)                                                            \
    do {                                                                      \
        _Pragma("unroll") for (int kk = 0; kk < 2; ++kk) {                    \
            bf16x8 av[8], bv[4];                                              \
            _Pragma("unroll") for (int ni = 0; ni < 4; ++ni) {                \
                const int row = wc * 64 + ni * 16 + r15;                      \
                const int off =                                               \
                    row * 128 + ((kk * 64 + kgrp * 16) ^ ((row & 7) << 4));   \
                bv[ni] = *(const bf16x8*)(lds + 32768 + (S) * 65536 + off);   \
            }                                                                 \
            _Pragma("unroll") for (int mi = 0; mi < 8; ++mi) {                \
                const int row = wr * 128 + mi * 16 + r15;                     \
                const int off =                                               \
                    row * 128 + ((kk * 64 + kgrp * 16) ^ ((row & 7) << 4));   \
                av[mi] = *(const bf16x8*)(lds + (S) * 65536 + off);           \
            }                                                                 \
            _Pragma("unroll") for (int mi = 0; mi < 8; ++mi)                  \
                _Pragma("unroll") for (int ni = 0; ni < 4; ++ni)              \
                    acc[mi][ni] = __builtin_amdgcn_mfma_f32_16x16x32_bf16(    \
                        av[mi], bv[ni], acc[mi][ni], 0, 0, 0);                \
        }                                                                     \
    } while (0)

    STAGE(0, 0);
    __syncthreads();  // buf0 ready
#pragma unroll
    for (int kt = 0; kt < 7; ++kt) {
        STAGE((kt + 1) & 1, kt + 1);  // issue next-tile loads first
        COMPUTE(kt & 1);              // MFMA hides the load returns
        __syncthreads();              // drain + all waves done with side kt&1
    }
    COMPUTE(1);
#undef STAGE
#undef COMPUTE

    // ---- epilogue: row-max (fold ni + 16-lane shfl), diagonal masked ----
    // D layout: col = wc*64 + ni*16 + r15, row = wr*128 + mi*16 + kgrp*4 + r
    const bool diag = (tm == tn);
    float rmx[8][4];
#pragma unroll
    for (int mi = 0; mi < 8; ++mi) {
#pragma unroll
        for (int r = 0; r < 4; ++r) {
            const int rl = wr * 128 + mi * 16 + kgrp * 4 + r;
            float v = -2.0f;
#pragma unroll
            for (int ni = 0; ni < 4; ++ni) {
                float e = acc[mi][ni][r];
                if (diag && (wc * 64 + ni * 16 + r15) == rl) e = -2.0f;
                v = fmaxf(v, e);
            }
            v = fmaxf(v, __shfl_xor(v, 1));
            v = fmaxf(v, __shfl_xor(v, 2));
            v = fmaxf(v, __shfl_xor(v, 4));
            v = fmaxf(v, __shfl_xor(v, 8));
            rmx[mi][r] = v;
        }
    }
    __syncthreads();  // all LDS tile reads done; safe to alias rbuf onto lds
    float* rbuf = (float*)lds;  // [256 rows][4 wc]
    if (r15 == 0) {
#pragma unroll
        for (int mi = 0; mi < 8; ++mi)
#pragma unroll
            for (int r = 0; r < 4; ++r)
                rbuf[(wr * 128 + mi * 16 + kgrp * 4 + r) * 4 + wc] = rmx[mi][r];
    }
    __syncthreads();
    if (tid < 256) {
        const float v = fmaxf(fmaxf(rbuf[tid * 4 + 0], rbuf[tid * 4 + 1]),
                              fmaxf(rbuf[tid * 4 + 2], rbuf[tid * 4 + 3]));
        partial[((size_t)b * TT + tm * 256 + tid) * NT2 + tn] = v;
    }
}

// ---------------- K3: reduce partial maxes + gate_nn scale + final write ----------------
// 256 threads = 4 waves; one wave per row; reads bf16 PO, writes f32 out.
__global__ __launch_bounds__(256) void k3_scale(float* __restrict__ out,
                                                const unsigned short* __restrict__ po,
                                                const float* __restrict__ partial,
                                                const float* __restrict__ p_lsn,
                                                const float* __restrict__ p_lwn) {
    const int row = blockIdx.x * 4 + (threadIdx.x >> 6);
    const int lane = threadIdx.x & 63;
    const float sigma_nn = softplus_f(p_lsn[0]);
    const float w_nn = softplus_f(p_lwn[0]);

    float p = partial[(size_t)row * NT2 + (lane & 7)];
    p = fmaxf(p, __shfl_xor(p, 1));
    p = fmaxf(p, __shfl_xor(p, 2));
    p = fmaxf(p, __shfl_xor(p, 4));
    const float g = 1.0f + w_nn * tanh_fast(sigma_nn * 0.5f * (1.0f - p));

    const size_t base = (size_t)row * DD + lane * 8;
    ushort4 p0 = *reinterpret_cast<const ushort4*>(po + base);
    ushort4 p1 = *reinterpret_cast<const ushort4*>(po + base + 4);
    float4 o0, o1;
    o0.x = bf2f(p0.x) * g; o0.y = bf2f(p0.y) * g;
    o0.z = bf2f(p0.z) * g; o0.w = bf2f(p0.w) * g;
    o1.x = bf2f(p1.x) * g; o1.y = bf2f(p1.y) * g;
    o1.z = bf2f(p1.z) * g; o1.w = bf2f(p1.w) * g;
    *reinterpret_cast<float4*>(out + base) = o0;
    *reinterpret_cast<float4*>(out + base + 4) = o1;
}

extern "C" void kernel_launch(void* const* d_in, const int* in_sizes, int n_in,
                              void* d_out, int out_size, void* d_ws, size_t ws_size,
                              hipStream_t stream) {
    const float* x = (const float*)d_in[0];
    const float* ema_mean = (const float*)d_in[1];
    const float* ema_sq = (const float*)d_in[2];
    const float* ema_out = (const float*)d_in[3];
    const float* log_tau = (const float*)d_in[4];
    const float* log_beta_up = (const float*)d_in[5];
    const float* log_beta_dn = (const float*)d_in[6];
    const float* log_gamma = (const float*)d_in[7];
    const float* log_sigma_nn = (const float*)d_in[8];
    const float* log_w_nn = (const float*)d_in[9];

    // ws layout: XN bf16 [B*T*D] (16.78 MB) | PO bf16 [B*T*D] (16.78 MB)
    //            | partial f32[B*T][NT2] (512 KB)
    char* ws = (char*)d_ws;
    unsigned short* XN = (unsigned short*)ws;
    unsigned short* PO = (unsigned short*)(ws + 16777216);
    float* partial = (float*)(ws + 33554432);
    float* out = (float*)d_out;

    hipLaunchKernelGGL(k1_elem, dim3(BB * TT / 4), dim3(256), 0, stream, x, ema_mean, ema_sq,
                       ema_out, log_tau, log_beta_up, log_beta_dn, log_gamma, XN, PO);
    hipLaunchKernelGGL(k2_nn, dim3(BB * 64), dim3(512), 0, stream, XN, partial);
    hipLaunchKernelGGL(k3_scale, dim3(BB * TT / 4), dim3(256), 0, stream, out, PO, partial,
                       log_sigma_nn, log_w_nn);
}